// Round 1
// 723.284 us; speedup vs baseline: 1.0795x; 1.0795x over previous
//
#include <hip/hip_runtime.h>
#include <math.h>

#define IN_DIM 128
#define HID_DIM 64

typedef __attribute__((ext_vector_type(8))) short short8;   // 8 bf16 (4 VGPRs)
typedef __attribute__((ext_vector_type(4))) float floatx4;  // MFMA C/D frag

// fp32 -> bf16 round-to-nearest-even
__device__ __forceinline__ short f2bf(float f) {
    unsigned u = __float_as_uint(f);
    u += 0x7FFFu + ((u >> 16) & 1u);
    return (short)(u >> 16);
}

__device__ __forceinline__ short8 pack_bf16(float4 f0, float4 f1) {
    short8 r;
    r[0] = f2bf(f0.x); r[1] = f2bf(f0.y); r[2] = f2bf(f0.z); r[3] = f2bf(f0.w);
    r[4] = f2bf(f1.x); r[5] = f2bf(f1.y); r[6] = f2bf(f1.z); r[7] = f2bf(f1.w);
    return r;
}

// fast tanh: tanh(x) = sign(x)*(1-z)/(1+z), z = exp(-2|x|)
__device__ __forceinline__ float fast_tanh(float x) {
    float ax = fabsf(x);
    float z  = __expf(-2.0f * ax);
    float t  = (1.0f - z) * __builtin_amdgcn_rcpf(1.0f + z);
    return copysignf(t, x);
}

// ---------------------------------------------------------------------------
// Fused kernel: ONE WAVE PER SEGMENT (batch sorted -> rows [lo,hi) contiguous).
// H is streamed from HBM exactly once (512 MB total vs 1 GB for the old
// 2-kernel pipeline). Per 16-row tile:
//   pass A (score): rows -> bf16 A-frags (m = lane&15 = row, k = quad*8+j,
//     verified m89/m120 layout), MFMA vs register-resident w1 frags,
//     epilogue s = w2 . tanh(X) via per-lane partials + 16-lane butterfly,
//     e = exp(s)  (|s| <= ||w2||_1 ~ 6.4, no overflow; softmax ratio is
//     mathematically identical without the max-subtraction pass).
//     e for all 16 rows broadcast to every lane with 16 compile-time shfls.
//   pass B (accumulate): re-read the SAME 16 rows (8 KB, L1/L2-resident:
//     ~12 waves/CU x 8 KB window ~ 3 MB/XCD < 4 MB L2) in dim-owner layout
//     (lane owns dims 2*lane, 2*lane+1 -> float2, perfectly coalesced) and
//     FMA e*h into f32 registers. L2 pays for the re-read, HBM does not.
// Exclusive segment ownership -> no atomics, no e_arr, no workspace, and the
// normalized result out[g] = acc/sum(e) is stored directly (empty segment ->
// zeros, matching the reference's isfinite guard).
// ---------------------------------------------------------------------------
extern "C" __global__ __launch_bounds__(256, 3) void k_fused(
    const float* __restrict__ H, const float* __restrict__ w1,
    const float* __restrict__ w2, const int* __restrict__ batch,
    float* __restrict__ out, int n, int G)
{
    const int wave = threadIdx.x >> 6;
    const int lane = threadIdx.x & 63;
    const int col  = lane & 15;
    const int quad = lane >> 4;
    const int g    = blockIdx.x * 4 + wave;
    if (g >= G) return;                      // wave-uniform, no barriers used

    // segment bounds: lower_bound(g), lower_bound(g+1). Uniform across the
    // wave -> scalarized by the compiler; batch is L2-hot.
    int lo = 0, hi = n;
    while (lo < hi) { int mid = (lo + hi) >> 1; if (batch[mid] < g) lo = mid + 1; else hi = mid; }
    int lo2 = lo, hi2 = n;
    while (lo2 < hi2) { int mid = (lo2 + hi2) >> 1; if (batch[mid] < g + 1) lo2 = mid + 1; else hi2 = mid; }
    const int cnt = lo2 - lo;

    float* og = out + (size_t)g * IN_DIM;
    const int d0 = lane * 2;                 // this lane's 2 output dims

    if (cnt == 0) {                          // empty segment -> zeros
        *(float2*)(og + d0) = make_float2(0.f, 0.f);
        return;
    }

    // ---- w1 fragments (B operand): bf[t][c], t = n-tile, c = k-chunk ----
    // B[k][n]: n = lane&15 (hidden idx within tile), k = quad*8 + j + c*32.
    short8 bf[4][4];
    {
        const float* wb = w1 + (size_t)col * IN_DIM + quad * 8;
#pragma unroll
        for (int t = 0; t < 4; ++t) {
            const float* wt = wb + t * 16 * IN_DIM;
#pragma unroll
            for (int c = 0; c < 4; ++c) {
                float4 f0 = *(const float4*)(wt + c * 32);
                float4 f1 = *(const float4*)(wt + c * 32 + 4);
                bf[t][c] = pack_bf16(f0, f1);
            }
        }
    }
    float w2v[4];
#pragma unroll
    for (int t = 0; t < 4; ++t) w2v[t] = w2[t * 16 + col];

    float accx = 0.f, accy = 0.f, esum = 0.f;

    for (int t0 = 0; t0 < cnt; t0 += 16) {
        const int rem = cnt - t0;            // rows valid in this tile (>=1)

        // ---- pass A: scores for rows lo+t0 .. lo+t0+15 (clamped) ----
        int row = t0 + col;
        if (row >= cnt) row = cnt - 1;       // duplicate last row, e masked
        const float* hr = H + (size_t)(lo + row) * IN_DIM + quad * 8;

        floatx4 acc[4];
#pragma unroll
        for (int t = 0; t < 4; ++t) acc[t] = (floatx4){0.f, 0.f, 0.f, 0.f};

#pragma unroll
        for (int c = 0; c < 4; ++c) {
            float4 f0 = *(const float4*)(hr + c * 32);
            float4 f1 = *(const float4*)(hr + c * 32 + 4);
            short8 a = pack_bf16(f0, f1);
#pragma unroll
            for (int t = 0; t < 4; ++t)
                acc[t] = __builtin_amdgcn_mfma_f32_16x16x32_bf16(
                    a, bf[t][c], acc[t], 0, 0, 0);
        }

        // epilogue: s for tile-row (quad*4 + r); butterfly over the 16 cols
        // (hidden dim); xor masks 1/2/4/8 stay inside each 16-lane group.
        float e4[4];
#pragma unroll
        for (int r = 0; r < 4; ++r) {
            float p = 0.f;
#pragma unroll
            for (int t = 0; t < 4; ++t)
                p = fmaf(w2v[t], fast_tanh(acc[t][r]), p);
            p += __shfl_xor(p, 1);
            p += __shfl_xor(p, 2);
            p += __shfl_xor(p, 4);
            p += __shfl_xor(p, 8);
            e4[r] = __expf(p);
        }

        // broadcast all 16 row-e's to every lane (compile-time src lanes):
        // tile-row q*4+r lives in e4[r] of lanes quad==q; take lane q*16.
        float e_all[16];
#pragma unroll
        for (int r = 0; r < 4; ++r)
#pragma unroll
            for (int q = 0; q < 4; ++q)
                e_all[q * 4 + r] = __shfl(e4[r], q * 16);

        // mask padded rows, accumulate denominator (identical on all lanes)
#pragma unroll
        for (int j = 0; j < 16; ++j) {
            if (j >= rem) e_all[j] = 0.f;
            esum += e_all[j];
        }

        // ---- pass B: weighted accumulation, dim-owner layout, L2-hot ----
        const int m = rem < 16 ? rem : 16;
        const float* hb = H + (size_t)(lo + t0) * IN_DIM + d0;
#pragma unroll
        for (int j = 0; j < 16; ++j) {
            int jr = j < m ? j : m - 1;      // clamp (stays inside H); e=0
            float2 h = *(const float2*)(hb + (size_t)jr * IN_DIM);
            accx = fmaf(e_all[j], h.x, accx);
            accy = fmaf(e_all[j], h.y, accy);
        }
    }

    const float inv = 1.0f / esum;           // cnt>0 -> esum>0 (e=exp(s)>0)
    *(float2*)(og + d0) = make_float2(accx * inv, accy * inv);
}

// ---------------------------------------------------------------------------
// Inputs: H [N,128] f32, w1 [64,128] f32, w2 [1,64] f32, batch [N] int32
// (sorted), size scalar (ignored; G derived from out_size). Workspace unused.
// ---------------------------------------------------------------------------
extern "C" void kernel_launch(void* const* d_in, const int* in_sizes, int n_in,
                              void* d_out, int out_size, void* d_ws, size_t ws_size,
                              hipStream_t stream)
{
    const float* H     = (const float*)d_in[0];
    const float* w1    = (const float*)d_in[1];
    const float* w2    = (const float*)d_in[2];
    const int*   batch = (const int*)d_in[3];
    float*       out   = (float*)d_out;

    int n = in_sizes[0] / IN_DIM;   // 1,000,000
    int G = out_size / IN_DIM;      // 10,000

    int blocks = (G + 3) / 4;       // 4 waves/block, one segment per wave
    k_fused<<<blocks, 256, 0, stream>>>(H, w1, w2, batch, out, n, G);
}